// Round 10
// baseline (206.172 us; speedup 1.0000x reference)
//
#include <hip/hip_runtime.h>
#include <hip/hip_bf16.h>

// GPT-2 attention block. Inputs/outputs fp32; internal bf16 MFMA, fp32 accum.
// B=4, S=1024, D=1024, H=16, hd=64.
//
// R10: GEMM core reverted to R8's BK=32 (16 KB LDS, occupancy > conflict-
//      freedom, per m132 lesson), keeping R9's packed epilogue + fused prep.
//      Attention: double-buffered K staging (DMA issued one iter ahead ->
//      barrier drain hidden), kB fragments shared across the paired q-tiles,
//      vB held in registers across both PV passes. LDS 64 KB, 2 blocks/CU.

typedef __bf16 bf16x8 __attribute__((ext_vector_type(8)));
typedef float f32x4 __attribute__((ext_vector_type(4)));

__device__ __forceinline__ void load_lds16(const void* g, void* l) {
  __builtin_amdgcn_global_load_lds(
      (const __attribute__((address_space(1))) void*)g,
      (__attribute__((address_space(3))) void*)l, 16, 0, 0);
}

// ---------------- fused prep: transpose w_attn, w_proj; convert x ----------------
__global__ __launch_bounds__(256) void prep(
    const float* __restrict__ x, const float* __restrict__ w_attn,
    const float* __restrict__ w_proj, __bf16* __restrict__ Xb,
    __bf16* __restrict__ WT_attn, __bf16* __restrict__ WT_proj) {
  __shared__ __bf16 tile[32][33];
  const int blk = blockIdx.x;
  const int tid = threadIdx.x;
  if (blk < 4096) {  // transpose (block-uniform branch)
    const float* W;
    __bf16* WT;
    int n0, k0, N;
    if (blk < 3072) {
      W = w_attn; WT = WT_attn; N = 3072;
      n0 = (blk % 96) * 32; k0 = (blk / 96) * 32;
    } else {
      W = w_proj; WT = WT_proj; N = 1024;
      const int t = blk - 3072;
      n0 = (t & 31) * 32; k0 = (t >> 5) * 32;
    }
    const int tx = tid & 31, ty = tid >> 5;
#pragma unroll
    for (int j = 0; j < 32; j += 8)
      tile[ty + j][tx] = (__bf16)W[(size_t)(k0 + ty + j) * N + n0 + tx];
    __syncthreads();
#pragma unroll
    for (int j = 0; j < 32; j += 8)
      WT[(size_t)(n0 + ty + j) * 1024 + k0 + tx] = tile[tx][ty + j];
  } else {  // x -> bf16, 16 elems/thread
    const size_t i = (size_t)(blk - 4096) * 4096 + tid * 16;
    const float4* xp = (const float4*)(x + i);
    float4 a = xp[0], b = xp[1], c = xp[2], d = xp[3];
    bf16x8 o0, o1;
    o0[0] = (__bf16)a.x; o0[1] = (__bf16)a.y; o0[2] = (__bf16)a.z; o0[3] = (__bf16)a.w;
    o0[4] = (__bf16)b.x; o0[5] = (__bf16)b.y; o0[6] = (__bf16)b.z; o0[7] = (__bf16)b.w;
    o1[0] = (__bf16)c.x; o1[1] = (__bf16)c.y; o1[2] = (__bf16)c.z; o1[3] = (__bf16)c.w;
    o1[4] = (__bf16)d.x; o1[5] = (__bf16)d.y; o1[6] = (__bf16)d.z; o1[7] = (__bf16)d.w;
    *(bf16x8*)(Xb + i) = o0;
    *(bf16x8*)(Xb + i + 8) = o1;
  }
}

// ---------------- V transpose: VT[bh][d][s] from Vr[s_global][1024] ----------------
__global__ __launch_bounds__(256) void transpose_v(
    const __bf16* __restrict__ Vr, __bf16* __restrict__ VT) {
  const int lane = threadIdx.x & 63, wave = threadIdx.x >> 6;
  const int bh = blockIdx.x >> 4;
  const int kb = (blockIdx.x & 15) * 64;
  const int b = bh >> 4, h = bh & 15;
  const __bf16* src =
      Vr + (size_t)(b * 1024 + kb + lane) * 1024 + h * 64 + wave * 16;
  bf16x8 v0 = *(const bf16x8*)src;
  bf16x8 v1 = *(const bf16x8*)(src + 8);
  __bf16* dst = VT + ((size_t)bh * 64 + wave * 16) * 1024 + kb + lane;
#pragma unroll
  for (int i = 0; i < 8; ++i) {
    dst[(size_t)i * 1024] = v0[i];
    dst[(size_t)(i + 8) * 1024] = v1[i];
  }
}

// ================= GEMM core (R8: BK=32, 16 KB LDS) =================
#define GEMM_CORE(A_, BT_, K_)                                                   \
  __shared__ __bf16 sA[128 * 32];                                               \
  __shared__ __bf16 sB[128 * 32];                                               \
  const int tid = threadIdx.x;                                                  \
  const int lane = tid & 63;                                                    \
  const int wave = tid >> 6;                                                    \
  const int waveM = wave >> 1, waveN = wave & 1;                                \
  const int quad = lane >> 4;                                                   \
  const int l16 = lane & 15;                                                    \
  const int rowBase = blockIdx.y * 128;                                         \
  const int colBase = blockIdx.x * 128;                                         \
  const int rIn = lane >> 2;                                                    \
  const int sIn = lane & 3;                                                     \
  const int gc = sIn ^ (rIn & 3) ^ ((rIn >> 2) & 3);                            \
  const int readSlot = quad ^ (l16 & 3) ^ ((l16 >> 2) & 3);                     \
  f32x4 acc[4][4] = {};                                                         \
  for (int k0 = 0; k0 < K_; k0 += 32) {                                         \
    __syncthreads();                                                            \
    _Pragma("unroll") for (int j = 0; j < 2; ++j) {                             \
      const int rb = wave * 32 + j * 16;                                        \
      load_lds16(&A_[(size_t)(rowBase + rb + rIn) * K_ + k0 + gc * 8],          \
                 &sA[rb * 32]);                                                 \
      load_lds16(&BT_[(size_t)(colBase + rb + rIn) * K_ + k0 + gc * 8],         \
                 &sB[rb * 32]);                                                 \
    }                                                                           \
    __syncthreads();                                                            \
    bf16x8 af[4], bfr[4];                                                       \
    _Pragma("unroll") for (int mt = 0; mt < 4; ++mt)                            \
      af[mt] = *(const bf16x8*)(&sA[(waveM * 64 + mt * 16 + l16) * 32 +         \
                                    readSlot * 8]);                             \
    _Pragma("unroll") for (int nt = 0; nt < 4; ++nt)                            \
      bfr[nt] = *(const bf16x8*)(&sB[(waveN * 64 + nt * 16 + l16) * 32 +        \
                                     readSlot * 8]);                            \
    _Pragma("unroll") for (int mt = 0; mt < 4; ++mt)                            \
    _Pragma("unroll") for (int nt = 0; nt < 4; ++nt)                            \
      acc[mt][nt] = __builtin_amdgcn_mfma_f32_16x16x32_bf16(                    \
          af[mt], bfr[nt], acc[mt][nt], 0, 0, 0);                               \
  }

// ---------------- GEMM1: QKV, epilogue writes packed Qp/Kp/Vr ----------------
__global__ __launch_bounds__(256) void gemm_qkv(
    const __bf16* __restrict__ A, const __bf16* __restrict__ BT,
    const float* __restrict__ bias, __bf16* __restrict__ Qp,
    __bf16* __restrict__ Kp, __bf16* __restrict__ Vr) {
  GEMM_CORE(A, BT, 1024)
  const int seg = colBase >> 10;  // 0=Q 1=K 2=V (block-uniform)
#pragma unroll
  for (int mt = 0; mt < 4; ++mt) {
    const int row0 = rowBase + waveM * 64 + mt * 16 + quad * 4;
#pragma unroll
    for (int nt = 0; nt < 4; ++nt) {
      const int col = colBase + waveN * 64 + nt * 16 + l16;
      const float bv = bias[col];
      const int cc = col & 1023;
#pragma unroll
      for (int r = 0; r < 4; ++r) {
        const int row = row0 + r;
        const float v = acc[mt][nt][r] + bv;
        if (seg == 2) {
          Vr[(size_t)row * 1024 + cc] = (__bf16)v;
        } else {
          const int bh = ((row >> 10) << 4) + (cc >> 6);
          __bf16* dst = (seg == 0) ? Qp : Kp;
          dst[((size_t)bh << 16) + (size_t)(row & 1023) * 64 + (cc & 63)] =
              (__bf16)v;
        }
      }
    }
  }
}

// ---------------- GEMM2: out = A @ WT^T + bias (fp32 out) ----------------
__global__ __launch_bounds__(256) void gemm_out(
    const __bf16* __restrict__ A, const __bf16* __restrict__ BT,
    const float* __restrict__ bias, float* __restrict__ C) {
  GEMM_CORE(A, BT, 1024)
#pragma unroll
  for (int mt = 0; mt < 4; ++mt) {
    const int row = rowBase + waveM * 64 + mt * 16 + quad * 4;
#pragma unroll
    for (int nt = 0; nt < 4; ++nt) {
      const int col = colBase + waveN * 64 + nt * 16 + l16;
      const float bv = bias[col];
#pragma unroll
      for (int r = 0; r < 4; ++r)
        C[(size_t)(row + r) * 1024 + col] = acc[mt][nt][r] + bv;
    }
  }
}

// ---------------- paired flash attention, K-dbuf + shared fragments ----------------
// Block = (bh, pair pr): q-tiles pr and 15-pr. Per 128-key tile:
//   barrier1 -> issue K-DMA(kt+1 -> other buf) + V-DMA(kt) -> QK both sides
//   (shared kB) -> exp/scatter B -> barrier2 (V staged, drains are warm) ->
//   PV B (vB kept in regs) -> exp/scatter A -> PV A (reuse vB).
__global__ __launch_bounds__(256, 2) void attn_mfma(
    const __bf16* __restrict__ Qp, const __bf16* __restrict__ Kp,
    const __bf16* __restrict__ VT, __bf16* __restrict__ Aout) {
  __shared__ __bf16 sK[2][128 * 64];   // 32 KB, double-buffered packed K
  __shared__ __bf16 sV[64 * 128];      // 16 KB
  __shared__ __bf16 sP[4][2048];       // 16 KB, per-wave P

  const int tid = threadIdx.x;
  const int lane = tid & 63;
  const int wave = tid >> 6;
  const int quad = lane >> 4;
  const int l16 = lane & 15;
  const int swq = l16 & 7;

  const int bh = blockIdx.x >> 3;
  const int pr = blockIdx.x & 7;
  const int b = bh >> 4, h = bh & 15;
  const int qbA = pr * 64, qbB = (15 - pr) * 64;
  const int ktA_max = pr >> 1, ktB_max = (15 - pr) >> 1;

  const __bf16* Qb = Qp + ((size_t)bh << 16);
  const __bf16* Kb = Kp + ((size_t)bh << 16);
  const __bf16* VTb = VT + (size_t)bh * 64 * 1024;

  bf16x8 qA0A, qA1A, qA0B, qA1B;
  {
    const __bf16* qr = Qb + (size_t)(qbA + wave * 16 + l16) * 64 + quad * 8;
    qA0A = *(const bf16x8*)qr;
    qA1A = *(const bf16x8*)(qr + 32);
    qr = Qb + (size_t)(qbB + wave * 16 + l16) * 64 + quad * 8;
    qA0B = *(const bf16x8*)qr;
    qA1B = *(const bf16x8*)(qr + 32);
  }

  f32x4 OA[4] = {}, OB[4] = {};
  float psA[4] = {0.f, 0.f, 0.f, 0.f}, psB[4] = {0.f, 0.f, 0.f, 0.f};
  __bf16* pw = sP[wave];

  const int krow = lane >> 3, kslot = lane & 7;  // K staging ids
  const int vrow = lane >> 4, vslot = lane & 15; // V staging ids

  // prologue: stage K tile 0 into buf 0
#pragma unroll
  for (int i = 0; i < 4; ++i) {
    const int rb = wave * 32 + i * 8;
    load_lds16(Kb + (size_t)(rb + krow) * 64 + ((kslot ^ krow) << 3),
               &sK[0][rb * 64]);
  }

  for (int kt = 0; kt <= ktB_max; ++kt) {
    const int cur = kt & 1;
    const int kb = kt * 128;
    __syncthreads();  // barrier1: prev compute done; K-DMA(kt->cur) drained

    if (kt < ktB_max) {  // K-DMA for next tile into other buffer
#pragma unroll
      for (int i = 0; i < 4; ++i) {
        const int rb = wave * 32 + i * 8;
        load_lds16(Kb + (size_t)(kb + 128 + rb + krow) * 64 + ((kslot ^ krow) << 3),
                   &sK[cur ^ 1][rb * 64]);
      }
    }
    // V-DMA for current tile (readers of prev V done per barrier1)
#pragma unroll
    for (int i = 0; i < 4; ++i) {
      const int db = wave * 16 + i * 4;
      const int d = db + vrow;
      load_lds16(VTb + (size_t)d * 1024 + kb + ((vslot ^ (d & 7)) << 3),
                 &sV[db * 128]);
    }

    const bool aAct = (kt <= ktA_max);
    const __bf16* kbuf = sK[cur];

    // ---- QK^T both sides, shared kB fragments
    f32x4 cB[8], cA[8];
#pragma unroll
    for (int n = 0; n < 8; ++n) {
      const int key = n * 16 + l16;
      bf16x8 k0 = *(const bf16x8*)(&kbuf[key * 64 + ((quad ^ swq) << 3)]);
      bf16x8 k1 = *(const bf16x8*)(&kbuf[key * 64 + (((quad + 4) ^ swq) << 3)]);
      f32x4 c = {};
      c = __builtin_amdgcn_mfma_f32_16x16x32_bf16(qA0B, k0, c, 0, 0, 0);
      c = __builtin_amdgcn_mfma_f32_16x16x32_bf16(qA1B, k1, c, 0, 0, 0);
      cB[n] = c;
      if (aAct) {
        f32x4 d = {};
        d = __builtin_amdgcn_mfma_f32_16x16x32_bf16(qA0A, k0, d, 0, 0, 0);
        d = __builtin_amdgcn_mfma_f32_16x16x32_bf16(qA1A, k1, d, 0, 0, 0);
        cA[n] = d;
      }
    }

    // ---- side B: scale, mask, exp, scatter
    {
      const int kb8 = l16 >> 3, lo = l16 & 7;
#pragma unroll
      for (int n = 0; n < 8; ++n) {
        const int kg = kb + n * 16 + l16;
        const int chunk = n * 2 + kb8;
#pragma unroll
        for (int r = 0; r < 4; ++r) {
          float s = cB[n][r] * 0.125f;
          if (kt == ktB_max && kg > qbB + wave * 16 + quad * 4 + r) s = -1.0e30f;
          const float p = __expf(fminf(s, 60.0f));
          psB[r] += p;
          const int q = quad * 4 + r;
          pw[q * 128 + ((chunk ^ (q & 7)) << 3) + lo] = (__bf16)p;
        }
      }
    }

    __syncthreads();  // barrier2: sV staged (V-DMA had QK+exp time in flight)

    // ---- PV side B; keep vB fragments for side A
    bf16x8 vBreg[4][4];
#pragma unroll
    for (int cc = 0; cc < 4; ++cc) {
      bf16x8 pA = *(const bf16x8*)(&pw[l16 * 128 + (((cc * 4 + quad) ^ swq) << 3)]);
#pragma unroll
      for (int nt = 0; nt < 4; ++nt) {
        vBreg[cc][nt] = *(const bf16x8*)(&sV[(nt * 16 + l16) * 128 +
                                             (((cc * 4 + quad) ^ swq) << 3)]);
        OB[nt] = __builtin_amdgcn_mfma_f32_16x16x32_bf16(pA, vBreg[cc][nt],
                                                         OB[nt], 0, 0, 0);
      }
    }

    // ---- side A (reuses vB regs; pw overwrite is in-wave ordered)
    if (aAct) {
      const int kb8 = l16 >> 3, lo = l16 & 7;
#pragma unroll
      for (int n = 0; n < 8; ++n) {
        const int kg = kb + n * 16 + l16;
        const int chunk = n * 2 + kb8;
#pragma unroll
        for (int r = 0; r < 4; ++r) {
          float s = cA[n][r] * 0.125f;
          if (kt == ktA_max && kg > qbA + wave * 16 + quad * 4 + r) s = -1.0e30f;
          const float p = __expf(fminf(s, 60.0f));
          psA[r] += p;
          const int q = quad * 4 + r;
          pw[q * 128 + ((chunk ^ (q & 7)) << 3) + lo] = (__bf16)p;
        }
      }
#pragma unroll
      for (int cc = 0; cc < 4; ++cc) {
        bf16x8 pA = *(const bf16x8*)(&pw[l16 * 128 + (((cc * 4 + quad) ^ swq) << 3)]);
#pragma unroll
        for (int nt = 0; nt < 4; ++nt)
          OA[nt] = __builtin_amdgcn_mfma_f32_16x16x32_bf16(pA, vBreg[cc][nt],
                                                           OA[nt], 0, 0, 0);
      }
    }
  }

  // ---- epilogue
  float invA[4], invB[4];
#pragma unroll
  for (int r = 0; r < 4; ++r) {
    float pa = psA[r], pb = psB[r];
    pa += __shfl_xor(pa, 1); pb += __shfl_xor(pb, 1);
    pa += __shfl_xor(pa, 2); pb += __shfl_xor(pb, 2);
    pa += __shfl_xor(pa, 4); pb += __shfl_xor(pb, 4);
    pa += __shfl_xor(pa, 8); pb += __shfl_xor(pb, 8);
    invA[r] = 1.0f / pa;
    invB[r] = 1.0f / pb;
  }
#pragma unroll
  for (int nt = 0; nt < 4; ++nt) {
#pragma unroll
    for (int r = 0; r < 4; ++r) {
      const int qA = qbA + wave * 16 + quad * 4 + r;
      const int qB = qbB + wave * 16 + quad * 4 + r;
      Aout[((size_t)b * 1024 + qA) * 1024 + h * 64 + nt * 16 + l16] =
          (__bf16)(OA[nt][r] * invA[r]);
      Aout[((size_t)b * 1024 + qB) * 1024 + h * 64 + nt * 16 + l16] =
          (__bf16)(OB[nt][r] * invB[r]);
    }
  }
}

// ---------------- launch ----------------
extern "C" void kernel_launch(void* const* d_in, const int* in_sizes, int n_in,
                              void* d_out, int out_size, void* d_ws,
                              size_t ws_size, hipStream_t stream) {
  const float* x      = (const float*)d_in[0];
  const float* w_attn = (const float*)d_in[1];
  const float* b_attn = (const float*)d_in[2];
  const float* w_proj = (const float*)d_in[3];
  const float* b_proj = (const float*)d_in[4];
  float* out = (float*)d_out;

  char* ws = (char*)d_ws;
  __bf16* WT_attn = (__bf16*)(ws);                  //  6 MB
  __bf16* WT_proj = (__bf16*)(ws + 6291456);        //  2 MB
  __bf16* Xb      = (__bf16*)(ws + 8388608);        //  8 MB (reused as VT)
  __bf16* Qp      = (__bf16*)(ws + 16777216);       //  8 MB [bh][s][64]
  __bf16* Kp      = (__bf16*)(ws + 25165824);       //  8 MB [bh][s][64]
  __bf16* Vr      = (__bf16*)(ws + 33554432);       //  8 MB [s_glob][1024]
  __bf16* Aattn   = (__bf16*)(ws + 41943040);       //  8 MB (end 50 MB)
  __bf16* VT      = Xb;  // x-as-bf16 dead after GEMM1

  prep<<<5120, 256, 0, stream>>>(x, w_attn, w_proj, Xb, WT_attn, WT_proj);
  gemm_qkv<<<dim3(24, 32), 256, 0, stream>>>(Xb, WT_attn, b_attn, Qp, Kp, Vr);
  transpose_v<<<1024, 256, 0, stream>>>(Vr, VT);
  attn_mfma<<<512, 256, 0, stream>>>(Qp, Kp, VT, Aattn);
  gemm_out<<<dim3(8, 32), 256, 0, stream>>>(Aattn, WT_proj, b_proj, out);
}

// Round 11
// 205.379 us; speedup vs baseline: 1.0039x; 1.0039x over previous
//
#include <hip/hip_runtime.h>
#include <hip/hip_bf16.h>

// GPT-2 attention block. Inputs/outputs fp32; internal bf16 MFMA, fp32 accum.
// B=4, S=1024, D=1024, H=16, hd=64.
//
// R11: GEMM = R8 core (BK=32) + packed epilogue (best known, ~43 us).
//      Attention = R9 paired structure with LDS-read dedup done right:
//      kB fragments read ONCE per iter (QK of both sides interleaved),
//      both P scatters precede a merged PV loop whose vB fragments are
//      transient (read once, feed OB and OA) -> 72 -> 40 b128 reads per
//      wave-iter, peak VGPR ~150 (R10's spill eliminated).

typedef __bf16 bf16x8 __attribute__((ext_vector_type(8)));
typedef float f32x4 __attribute__((ext_vector_type(4)));

__device__ __forceinline__ void load_lds16(const void* g, void* l) {
  __builtin_amdgcn_global_load_lds(
      (const __attribute__((address_space(1))) void*)g,
      (__attribute__((address_space(3))) void*)l, 16, 0, 0);
}

// ---------------- fused prep: transpose w_attn, w_proj; convert x ----------------
__global__ __launch_bounds__(256) void prep(
    const float* __restrict__ x, const float* __restrict__ w_attn,
    const float* __restrict__ w_proj, __bf16* __restrict__ Xb,
    __bf16* __restrict__ WT_attn, __bf16* __restrict__ WT_proj) {
  __shared__ __bf16 tile[32][33];
  const int blk = blockIdx.x;
  const int tid = threadIdx.x;
  if (blk < 4096) {  // transpose (block-uniform branch)
    const float* W;
    __bf16* WT;
    int n0, k0, N;
    if (blk < 3072) {
      W = w_attn; WT = WT_attn; N = 3072;
      n0 = (blk % 96) * 32; k0 = (blk / 96) * 32;
    } else {
      W = w_proj; WT = WT_proj; N = 1024;
      const int t = blk - 3072;
      n0 = (t & 31) * 32; k0 = (t >> 5) * 32;
    }
    const int tx = tid & 31, ty = tid >> 5;
#pragma unroll
    for (int j = 0; j < 32; j += 8)
      tile[ty + j][tx] = (__bf16)W[(size_t)(k0 + ty + j) * N + n0 + tx];
    __syncthreads();
#pragma unroll
    for (int j = 0; j < 32; j += 8)
      WT[(size_t)(n0 + ty + j) * 1024 + k0 + tx] = tile[tx][ty + j];
  } else {  // x -> bf16, 16 elems/thread
    const size_t i = (size_t)(blk - 4096) * 4096 + tid * 16;
    const float4* xp = (const float4*)(x + i);
    float4 a = xp[0], b = xp[1], c = xp[2], d = xp[3];
    bf16x8 o0, o1;
    o0[0] = (__bf16)a.x; o0[1] = (__bf16)a.y; o0[2] = (__bf16)a.z; o0[3] = (__bf16)a.w;
    o0[4] = (__bf16)b.x; o0[5] = (__bf16)b.y; o0[6] = (__bf16)b.z; o0[7] = (__bf16)b.w;
    o1[0] = (__bf16)c.x; o1[1] = (__bf16)c.y; o1[2] = (__bf16)c.z; o1[3] = (__bf16)c.w;
    o1[4] = (__bf16)d.x; o1[5] = (__bf16)d.y; o1[6] = (__bf16)d.z; o1[7] = (__bf16)d.w;
    *(bf16x8*)(Xb + i) = o0;
    *(bf16x8*)(Xb + i + 8) = o1;
  }
}

// ---------------- V transpose: VT[bh][d][s] from Vr[s_global][1024] ----------------
__global__ __launch_bounds__(256) void transpose_v(
    const __bf16* __restrict__ Vr, __bf16* __restrict__ VT) {
  const int lane = threadIdx.x & 63, wave = threadIdx.x >> 6;
  const int bh = blockIdx.x >> 4;
  const int kb = (blockIdx.x & 15) * 64;
  const int b = bh >> 4, h = bh & 15;
  const __bf16* src =
      Vr + (size_t)(b * 1024 + kb + lane) * 1024 + h * 64 + wave * 16;
  bf16x8 v0 = *(const bf16x8*)src;
  bf16x8 v1 = *(const bf16x8*)(src + 8);
  __bf16* dst = VT + ((size_t)bh * 64 + wave * 16) * 1024 + kb + lane;
#pragma unroll
  for (int i = 0; i < 8; ++i) {
    dst[(size_t)i * 1024] = v0[i];
    dst[(size_t)(i + 8) * 1024] = v1[i];
  }
}

// ================= GEMM core (R8: BK=32, 16 KB LDS) =================
#define GEMM_CORE(A_, BT_, K_)                                                   \
  __shared__ __bf16 sA[128 * 32];                                               \
  __shared__ __bf16 sB[128 * 32];                                               \
  const int tid = threadIdx.x;                                                  \
  const int lane = tid & 63;                                                    \
  const int wave = tid >> 6;                                                    \
  const int waveM = wave >> 1, waveN = wave & 1;                                \
  const int quad = lane >> 4;                                                   \
  const int l16 = lane & 15;                                                    \
  const int rowBase = blockIdx.y * 128;                                         \
  const int colBase = blockIdx.x * 128;                                         \
  const int rIn = lane >> 2;                                                    \
  const int sIn = lane & 3;                                                     \
  const int gc = sIn ^ (rIn & 3) ^ ((rIn >> 2) & 3);                            \
  const int readSlot = quad ^ (l16 & 3) ^ ((l16 >> 2) & 3);                     \
  f32x4 acc[4][4] = {};                                                         \
  for (int k0 = 0; k0 < K_; k0 += 32) {                                         \
    __syncthreads();                                                            \
    _Pragma("unroll") for (int j = 0; j < 2; ++j) {                             \
      const int rb = wave * 32 + j * 16;                                        \
      load_lds16(&A_[(size_t)(rowBase + rb + rIn) * K_ + k0 + gc * 8],          \
                 &sA[rb * 32]);                                                 \
      load_lds16(&BT_[(size_t)(colBase + rb + rIn) * K_ + k0 + gc * 8],         \
                 &sB[rb * 32]);                                                 \
    }                                                                           \
    __syncthreads();                                                            \
    bf16x8 af[4], bfr[4];                                                       \
    _Pragma("unroll") for (int mt = 0; mt < 4; ++mt)                            \
      af[mt] = *(const bf16x8*)(&sA[(waveM * 64 + mt * 16 + l16) * 32 +         \
                                    readSlot * 8]);                             \
    _Pragma("unroll") for (int nt = 0; nt < 4; ++nt)                            \
      bfr[nt] = *(const bf16x8*)(&sB[(waveN * 64 + nt * 16 + l16) * 32 +        \
                                     readSlot * 8]);                            \
    _Pragma("unroll") for (int mt = 0; mt < 4; ++mt)                            \
    _Pragma("unroll") for (int nt = 0; nt < 4; ++nt)                            \
      acc[mt][nt] = __builtin_amdgcn_mfma_f32_16x16x32_bf16(                    \
          af[mt], bfr[nt], acc[mt][nt], 0, 0, 0);                               \
  }

// ---------------- GEMM1: QKV, epilogue writes packed Qp/Kp/Vr ----------------
__global__ __launch_bounds__(256) void gemm_qkv(
    const __bf16* __restrict__ A, const __bf16* __restrict__ BT,
    const float* __restrict__ bias, __bf16* __restrict__ Qp,
    __bf16* __restrict__ Kp, __bf16* __restrict__ Vr) {
  GEMM_CORE(A, BT, 1024)
  const int seg = colBase >> 10;  // 0=Q 1=K 2=V (block-uniform)
#pragma unroll
  for (int mt = 0; mt < 4; ++mt) {
    const int row0 = rowBase + waveM * 64 + mt * 16 + quad * 4;
#pragma unroll
    for (int nt = 0; nt < 4; ++nt) {
      const int col = colBase + waveN * 64 + nt * 16 + l16;
      const float bv = bias[col];
      const int cc = col & 1023;
#pragma unroll
      for (int r = 0; r < 4; ++r) {
        const int row = row0 + r;
        const float v = acc[mt][nt][r] + bv;
        if (seg == 2) {
          Vr[(size_t)row * 1024 + cc] = (__bf16)v;
        } else {
          const int bh = ((row >> 10) << 4) + (cc >> 6);
          __bf16* dst = (seg == 0) ? Qp : Kp;
          dst[((size_t)bh << 16) + (size_t)(row & 1023) * 64 + (cc & 63)] =
              (__bf16)v;
        }
      }
    }
  }
}

// ---------------- GEMM2: out = A @ WT^T + bias (fp32 out) ----------------
__global__ __launch_bounds__(256) void gemm_out(
    const __bf16* __restrict__ A, const __bf16* __restrict__ BT,
    const float* __restrict__ bias, float* __restrict__ C) {
  GEMM_CORE(A, BT, 1024)
#pragma unroll
  for (int mt = 0; mt < 4; ++mt) {
    const int row = rowBase + waveM * 64 + mt * 16 + quad * 4;
#pragma unroll
    for (int nt = 0; nt < 4; ++nt) {
      const int col = colBase + waveN * 64 + nt * 16 + l16;
      const float bv = bias[col];
#pragma unroll
      for (int r = 0; r < 4; ++r)
        C[(size_t)(row + r) * 1024 + col] = acc[mt][nt][r] + bv;
    }
  }
}

// ---------------- paired flash attention, dedup'd LDS reads ----------------
// Block = (bh, pair pr): q-tiles pr and 15-pr (64 rows each). Per 128-key
// tile: barrier -> DMA K,V -> barrier -> QK both sides (kB read ONCE) ->
// exp/scatter B to pwB, A to pwA -> merged PV (vB read once -> OB + OA).
__global__ __launch_bounds__(256) void attn_mfma(
    const __bf16* __restrict__ Qp, const __bf16* __restrict__ Kp,
    const __bf16* __restrict__ VT, __bf16* __restrict__ Aout) {
  __shared__ __bf16 sK[128 * 64];      // 16 KB
  __shared__ __bf16 sV[64 * 128];      // 16 KB
  __shared__ __bf16 sP[4][2][2048];    // 32 KB: per-wave, per-side P

  const int tid = threadIdx.x;
  const int lane = tid & 63;
  const int wave = tid >> 6;
  const int quad = lane >> 4;
  const int l16 = lane & 15;
  const int swq = l16 & 7;

  const int bh = blockIdx.x >> 3;
  const int pr = blockIdx.x & 7;
  const int b = bh >> 4, h = bh & 15;
  const int qbA = pr * 64, qbB = (15 - pr) * 64;
  const int ktA_max = pr >> 1, ktB_max = (15 - pr) >> 1;

  const __bf16* Qb = Qp + ((size_t)bh << 16);
  const __bf16* Kb = Kp + ((size_t)bh << 16);
  const __bf16* VTb = VT + (size_t)bh * 64 * 1024;

  bf16x8 qA0A, qA1A, qA0B, qA1B;
  {
    const __bf16* qr = Qb + (size_t)(qbA + wave * 16 + l16) * 64 + quad * 8;
    qA0A = *(const bf16x8*)qr;
    qA1A = *(const bf16x8*)(qr + 32);
    qr = Qb + (size_t)(qbB + wave * 16 + l16) * 64 + quad * 8;
    qA0B = *(const bf16x8*)qr;
    qA1B = *(const bf16x8*)(qr + 32);
  }

  f32x4 OA[4] = {}, OB[4] = {};
  float psA[4] = {0.f, 0.f, 0.f, 0.f}, psB[4] = {0.f, 0.f, 0.f, 0.f};
  __bf16* pwB = sP[wave][0];
  __bf16* pwA = sP[wave][1];

  const int krow = lane >> 3, kslot = lane & 7;
  const int vrow = lane >> 4, vslot = lane & 15;

  for (int kt = 0; kt <= ktB_max; ++kt) {
    const int kb = kt * 128;
    __syncthreads();  // prior iter's sK/sV/pw reads complete

    // ---- DMA stage K: sK[key][slot s] = chunk s^(key&7)
#pragma unroll
    for (int i = 0; i < 4; ++i) {
      const int rb = wave * 32 + i * 8;
      load_lds16(Kb + (size_t)(kb + rb + krow) * 64 + ((kslot ^ krow) << 3),
                 &sK[rb * 64]);
    }
    // ---- DMA stage V^T: sV[d][slot s] = key-chunk s^(d&7)
#pragma unroll
    for (int i = 0; i < 4; ++i) {
      const int db = wave * 16 + i * 4;
      const int d = db + vrow;
      load_lds16(VTb + (size_t)d * 1024 + kb + ((vslot ^ (d & 7)) << 3),
                 &sV[db * 128]);
    }
    __syncthreads();  // staged

    const bool aAct = (kt <= ktA_max);

    // ---- QK^T both sides, kB fragments read once
    f32x4 cB[8], cA[8];
#pragma unroll
    for (int n = 0; n < 8; ++n) {
      const int key = n * 16 + l16;
      bf16x8 k0 = *(const bf16x8*)(&sK[key * 64 + ((quad ^ swq) << 3)]);
      bf16x8 k1 = *(const bf16x8*)(&sK[key * 64 + (((quad + 4) ^ swq) << 3)]);
      f32x4 c = {};
      c = __builtin_amdgcn_mfma_f32_16x16x32_bf16(qA0B, k0, c, 0, 0, 0);
      c = __builtin_amdgcn_mfma_f32_16x16x32_bf16(qA1B, k1, c, 0, 0, 0);
      cB[n] = c;
      if (aAct) {
        f32x4 d = {};
        d = __builtin_amdgcn_mfma_f32_16x16x32_bf16(qA0A, k0, d, 0, 0, 0);
        d = __builtin_amdgcn_mfma_f32_16x16x32_bf16(qA1A, k1, d, 0, 0, 0);
        cA[n] = d;
      }
    }

    // ---- side B: scale, mask, exp, scatter to pwB (frees cB)
    {
      const int kb8 = l16 >> 3, lo = l16 & 7;
#pragma unroll
      for (int n = 0; n < 8; ++n) {
        const int kg = kb + n * 16 + l16;
        const int chunk = n * 2 + kb8;
#pragma unroll
        for (int r = 0; r < 4; ++r) {
          float s = cB[n][r] * 0.125f;
          if (kt == ktB_max && kg > qbB + wave * 16 + quad * 4 + r) s = -1.0e30f;
          const float p = __expf(fminf(s, 60.0f));
          psB[r] += p;
          const int q = quad * 4 + r;
          pwB[q * 128 + ((chunk ^ (q & 7)) << 3) + lo] = (__bf16)p;
        }
      }
    }
    // ---- side A: scale, mask, exp, scatter to pwA (frees cA)
    if (aAct) {
      const int kb8 = l16 >> 3, lo = l16 & 7;
#pragma unroll
      for (int n = 0; n < 8; ++n) {
        const int kg = kb + n * 16 + l16;
        const int chunk = n * 2 + kb8;
#pragma unroll
        for (int r = 0; r < 4; ++r) {
          float s = cA[n][r] * 0.125f;
          if (kt == ktA_max && kg > qbA + wave * 16 + quad * 4 + r) s = -1.0e30f;
          const float p = __expf(fminf(s, 60.0f));
          psA[r] += p;
          const int q = quad * 4 + r;
          pwA[q * 128 + ((chunk ^ (q & 7)) << 3) + lo] = (__bf16)p;
        }
      }
    }

    // ---- merged PV: vB read once, feeds OB and OA (wave-local ordering)
#pragma unroll
    for (int cc = 0; cc < 4; ++cc) {
      const int slot = ((cc * 4 + quad) ^ swq) << 3;
      bf16x8 pB = *(const bf16x8*)(&pwB[l16 * 128 + slot]);
      bf16x8 pA;
      if (aAct) pA = *(const bf16x8*)(&pwA[l16 * 128 + slot]);
#pragma unroll
      for (int nt = 0; nt < 4; ++nt) {
        bf16x8 vB = *(const bf16x8*)(&sV[(nt * 16 + l16) * 128 + slot]);
        OB[nt] = __builtin_amdgcn_mfma_f32_16x16x32_bf16(pB, vB, OB[nt], 0, 0, 0);
        if (aAct)
          OA[nt] = __builtin_amdgcn_mfma_f32_16x16x32_bf16(pA, vB, OA[nt], 0, 0, 0);
      }
    }
  }

  // ---- epilogue
  float invA[4], invB[4];
#pragma unroll
  for (int r = 0; r < 4; ++r) {
    float pa = psA[r], pb = psB[r];
    pa += __shfl_xor(pa, 1); pb += __shfl_xor(pb, 1);
    pa += __shfl_xor(pa, 2); pb += __shfl_xor(pb, 2);
    pa += __shfl_xor(pa, 4); pb += __shfl_xor(pb, 4);
    pa += __shfl_xor(pa, 8); pb += __shfl_xor(pb, 8);
    invA[r] = 1.0f / pa;
    invB[r] = 1.0f / pb;
  }
#pragma unroll
  for (int nt = 0; nt < 4; ++nt) {
#pragma unroll
    for (int r = 0; r < 4; ++r) {
      const int qA = qbA + wave * 16 + quad * 4 + r;
      const int qB = qbB + wave * 16 + quad * 4 + r;
      Aout[((size_t)b * 1024 + qA) * 1024 + h * 64 + nt * 16 + l16] =
          (__bf16)(OA[nt][r] * invA[r]);
      Aout[((size_t)b * 1024 + qB) * 1024 + h * 64 + nt * 16 + l16] =
          (__bf16)(OB[nt][r] * invB[r]);
    }
  }
}

// ---------------- launch ----------------
extern "C" void kernel_launch(void* const* d_in, const int* in_sizes, int n_in,
                              void* d_out, int out_size, void* d_ws,
                              size_t ws_size, hipStream_t stream) {
  const float* x      = (const float*)d_in[0];
  const float* w_attn = (const float*)d_in[1];
  const float* b_attn = (const float*)d_in[2];
  const float* w_proj = (const float*)d_in[3];
  const float* b_proj = (const float*)d_in[4];
  float* out = (float*)d_out;

  char* ws = (char*)d_ws;
  __bf16* WT_attn = (__bf16*)(ws);                  //  6 MB
  __bf16* WT_proj = (__bf16*)(ws + 6291456);        //  2 MB
  __bf16* Xb      = (__bf16*)(ws + 8388608);        //  8 MB (reused as VT)
  __bf16* Qp      = (__bf16*)(ws + 16777216);       //  8 MB [bh][s][64]
  __bf16* Kp      = (__bf16*)(ws + 25165824);       //  8 MB [bh][s][64]
  __bf16* Vr      = (__bf16*)(ws + 33554432);       //  8 MB [s_glob][1024]
  __bf16* Aattn   = (__bf16*)(ws + 41943040);       //  8 MB (end 50 MB)
  __bf16* VT      = Xb;  // x-as-bf16 dead after GEMM1

  prep<<<5120, 256, 0, stream>>>(x, w_attn, w_proj, Xb, WT_attn, WT_proj);
  gemm_qkv<<<dim3(24, 32), 256, 0, stream>>>(Xb, WT_attn, b_attn, Qp, Kp, Vr);
  transpose_v<<<1024, 256, 0, stream>>>(Vr, VT);
  attn_mfma<<<512, 256, 0, stream>>>(Qp, Kp, VT, Aattn);
  gemm_out<<<dim3(8, 32), 256, 0, stream>>>(Aattn, WT_proj, b_proj, out);
}

// Round 12
// 179.625 us; speedup vs baseline: 1.1478x; 1.1434x over previous
//
#include <hip/hip_runtime.h>
#include <hip/hip_bf16.h>

// GPT-2 attention block. Inputs/outputs fp32; internal bf16 MFMA, fp32 accum.
// B=4, S=1024, D=1024, H=16, hd=64.
//
// R12: best-of assembly. GEMM core = R8 BK=32 (measured 43 us; BK=64 was
//      48.8, dbuf/dedup attn variants all regressed on occupancy). Attention
//      = R9 kernel verbatim (measured <=48.8 inside the 186 us run; the
//      R10/R11 LDS-dedup variants lost waves and ran 57+). Packed epilogue,
//      fused prep, transpose_v unchanged.

typedef __bf16 bf16x8 __attribute__((ext_vector_type(8)));
typedef float f32x4 __attribute__((ext_vector_type(4)));

__device__ __forceinline__ void load_lds16(const void* g, void* l) {
  __builtin_amdgcn_global_load_lds(
      (const __attribute__((address_space(1))) void*)g,
      (__attribute__((address_space(3))) void*)l, 16, 0, 0);
}

// ---------------- fused prep: transpose w_attn, w_proj; convert x ----------------
__global__ __launch_bounds__(256) void prep(
    const float* __restrict__ x, const float* __restrict__ w_attn,
    const float* __restrict__ w_proj, __bf16* __restrict__ Xb,
    __bf16* __restrict__ WT_attn, __bf16* __restrict__ WT_proj) {
  __shared__ __bf16 tile[32][33];
  const int blk = blockIdx.x;
  const int tid = threadIdx.x;
  if (blk < 4096) {  // transpose (block-uniform branch)
    const float* W;
    __bf16* WT;
    int n0, k0, N;
    if (blk < 3072) {
      W = w_attn; WT = WT_attn; N = 3072;
      n0 = (blk % 96) * 32; k0 = (blk / 96) * 32;
    } else {
      W = w_proj; WT = WT_proj; N = 1024;
      const int t = blk - 3072;
      n0 = (t & 31) * 32; k0 = (t >> 5) * 32;
    }
    const int tx = tid & 31, ty = tid >> 5;
#pragma unroll
    for (int j = 0; j < 32; j += 8)
      tile[ty + j][tx] = (__bf16)W[(size_t)(k0 + ty + j) * N + n0 + tx];
    __syncthreads();
#pragma unroll
    for (int j = 0; j < 32; j += 8)
      WT[(size_t)(n0 + ty + j) * 1024 + k0 + tx] = tile[tx][ty + j];
  } else {  // x -> bf16, 16 elems/thread
    const size_t i = (size_t)(blk - 4096) * 4096 + tid * 16;
    const float4* xp = (const float4*)(x + i);
    float4 a = xp[0], b = xp[1], c = xp[2], d = xp[3];
    bf16x8 o0, o1;
    o0[0] = (__bf16)a.x; o0[1] = (__bf16)a.y; o0[2] = (__bf16)a.z; o0[3] = (__bf16)a.w;
    o0[4] = (__bf16)b.x; o0[5] = (__bf16)b.y; o0[6] = (__bf16)b.z; o0[7] = (__bf16)b.w;
    o1[0] = (__bf16)c.x; o1[1] = (__bf16)c.y; o1[2] = (__bf16)c.z; o1[3] = (__bf16)c.w;
    o1[4] = (__bf16)d.x; o1[5] = (__bf16)d.y; o1[6] = (__bf16)d.z; o1[7] = (__bf16)d.w;
    *(bf16x8*)(Xb + i) = o0;
    *(bf16x8*)(Xb + i + 8) = o1;
  }
}

// ---------------- V transpose: VT[bh][d][s] from Vr[s_global][1024] ----------------
__global__ __launch_bounds__(256) void transpose_v(
    const __bf16* __restrict__ Vr, __bf16* __restrict__ VT) {
  const int lane = threadIdx.x & 63, wave = threadIdx.x >> 6;
  const int bh = blockIdx.x >> 4;
  const int kb = (blockIdx.x & 15) * 64;
  const int b = bh >> 4, h = bh & 15;
  const __bf16* src =
      Vr + (size_t)(b * 1024 + kb + lane) * 1024 + h * 64 + wave * 16;
  bf16x8 v0 = *(const bf16x8*)src;
  bf16x8 v1 = *(const bf16x8*)(src + 8);
  __bf16* dst = VT + ((size_t)bh * 64 + wave * 16) * 1024 + kb + lane;
#pragma unroll
  for (int i = 0; i < 8; ++i) {
    dst[(size_t)i * 1024] = v0[i];
    dst[(size_t)(i + 8) * 1024] = v1[i];
  }
}

// ================= GEMM core (R8: BK=32, 16 KB LDS) =================
#define GEMM_CORE(A_, BT_, K_)                                                   \
  __shared__ __bf16 sA[128 * 32];                                               \
  __shared__ __bf16 sB[128 * 32];                                               \
  const int tid = threadIdx.x;                                                  \
  const int lane = tid & 63;                                                    \
  const int wave = tid >> 6;                                                    \
  const int waveM = wave >> 1, waveN = wave & 1;                                \
  const int quad = lane >> 4;                                                   \
  const int l16 = lane & 15;                                                    \
  const int rowBase = blockIdx.y * 128;                                         \
  const int colBase = blockIdx.x * 128;                                         \
  const int rIn = lane >> 2;                                                    \
  const int sIn = lane & 3;                                                     \
  const int gc = sIn ^ (rIn & 3) ^ ((rIn >> 2) & 3);                            \
  const int readSlot = quad ^ (l16 & 3) ^ ((l16 >> 2) & 3);                     \
  f32x4 acc[4][4] = {};                                                         \
  for (int k0 = 0; k0 < K_; k0 += 32) {                                         \
    __syncthreads();                                                            \
    _Pragma("unroll") for (int j = 0; j < 2; ++j) {                             \
      const int rb = wave * 32 + j * 16;                                        \
      load_lds16(&A_[(size_t)(rowBase + rb + rIn) * K_ + k0 + gc * 8],          \
                 &sA[rb * 32]);                                                 \
      load_lds16(&BT_[(size_t)(colBase + rb + rIn) * K_ + k0 + gc * 8],         \
                 &sB[rb * 32]);                                                 \
    }                                                                           \
    __syncthreads();                                                            \
    bf16x8 af[4], bfr[4];                                                       \
    _Pragma("unroll") for (int mt = 0; mt < 4; ++mt)                            \
      af[mt] = *(const bf16x8*)(&sA[(waveM * 64 + mt * 16 + l16) * 32 +         \
                                    readSlot * 8]);                             \
    _Pragma("unroll") for (int nt = 0; nt < 4; ++nt)                            \
      bfr[nt] = *(const bf16x8*)(&sB[(waveN * 64 + nt * 16 + l16) * 32 +        \
                                     readSlot * 8]);                            \
    _Pragma("unroll") for (int mt = 0; mt < 4; ++mt)                            \
    _Pragma("unroll") for (int nt = 0; nt < 4; ++nt)                            \
      acc[mt][nt] = __builtin_amdgcn_mfma_f32_16x16x32_bf16(                    \
          af[mt], bfr[nt], acc[mt][nt], 0, 0, 0);                               \
  }

// ---------------- GEMM1: QKV, epilogue writes packed Qp/Kp/Vr ----------------
__global__ __launch_bounds__(256) void gemm_qkv(
    const __bf16* __restrict__ A, const __bf16* __restrict__ BT,
    const float* __restrict__ bias, __bf16* __restrict__ Qp,
    __bf16* __restrict__ Kp, __bf16* __restrict__ Vr) {
  GEMM_CORE(A, BT, 1024)
  const int seg = colBase >> 10;  // 0=Q 1=K 2=V (block-uniform)
#pragma unroll
  for (int mt = 0; mt < 4; ++mt) {
    const int row0 = rowBase + waveM * 64 + mt * 16 + quad * 4;
#pragma unroll
    for (int nt = 0; nt < 4; ++nt) {
      const int col = colBase + waveN * 64 + nt * 16 + l16;
      const float bv = bias[col];
      const int cc = col & 1023;
#pragma unroll
      for (int r = 0; r < 4; ++r) {
        const int row = row0 + r;
        const float v = acc[mt][nt][r] + bv;
        if (seg == 2) {
          Vr[(size_t)row * 1024 + cc] = (__bf16)v;
        } else {
          const int bh = ((row >> 10) << 4) + (cc >> 6);
          __bf16* dst = (seg == 0) ? Qp : Kp;
          dst[((size_t)bh << 16) + (size_t)(row & 1023) * 64 + (cc & 63)] =
              (__bf16)v;
        }
      }
    }
  }
}

// ---------------- GEMM2: out = A @ WT^T + bias (fp32 out) ----------------
__global__ __launch_bounds__(256) void gemm_out(
    const __bf16* __restrict__ A, const __bf16* __restrict__ BT,
    const float* __restrict__ bias, float* __restrict__ C) {
  GEMM_CORE(A, BT, 1024)
#pragma unroll
  for (int mt = 0; mt < 4; ++mt) {
    const int row = rowBase + waveM * 64 + mt * 16 + quad * 4;
#pragma unroll
    for (int nt = 0; nt < 4; ++nt) {
      const int col = colBase + waveN * 64 + nt * 16 + l16;
      const float bv = bias[col];
#pragma unroll
      for (int r = 0; r < 4; ++r)
        C[(size_t)(row + r) * 1024 + col] = acc[mt][nt][r] + bv;
    }
  }
}

// ---------------- paired flash attention (R9 kernel, verbatim) ----------------
__global__ __launch_bounds__(256) void attn_mfma(
    const __bf16* __restrict__ Qp, const __bf16* __restrict__ Kp,
    const __bf16* __restrict__ VT, __bf16* __restrict__ Aout) {
  __shared__ __bf16 sK[128 * 64];      // 16 KB, swizzled packed K lines
  __shared__ __bf16 sV[64 * 128];      // 16 KB, swizzled V^T
  __shared__ __bf16 sP[4 * 16 * 128];  // 16 KB, per-wave P regions

  const int tid = threadIdx.x;
  const int lane = tid & 63;
  const int wave = tid >> 6;
  const int quad = lane >> 4;
  const int l16 = lane & 15;
  const int swq = l16 & 7;

  const int bh = blockIdx.x >> 3;
  const int pr = blockIdx.x & 7;
  const int b = bh >> 4, h = bh & 15;
  const int qbA = pr * 64, qbB = (15 - pr) * 64;
  const int ktA_max = pr >> 1, ktB_max = (15 - pr) >> 1;

  const __bf16* Qb = Qp + ((size_t)bh << 16);
  const __bf16* Kb = Kp + ((size_t)bh << 16);
  const __bf16* VTb = VT + (size_t)bh * 64 * 1024;

  bf16x8 qA0A, qA1A, qA0B, qA1B;
  {
    const __bf16* qr = Qb + (size_t)(qbA + wave * 16 + l16) * 64 + quad * 8;
    qA0A = *(const bf16x8*)qr;
    qA1A = *(const bf16x8*)(qr + 32);
    qr = Qb + (size_t)(qbB + wave * 16 + l16) * 64 + quad * 8;
    qA0B = *(const bf16x8*)qr;
    qA1B = *(const bf16x8*)(qr + 32);
  }

  f32x4 OA[4] = {}, OB[4] = {};
  float psA[4] = {0.f, 0.f, 0.f, 0.f}, psB[4] = {0.f, 0.f, 0.f, 0.f};
  __bf16* pw = sP + wave * 2048;

  for (int kt = 0; kt <= ktB_max; ++kt) {
    const int kb = kt * 128;
    __syncthreads();  // prior iter's sK/sV reads complete

    // ---- DMA stage K: sK[key][slot s] = line chunk s^(key&7)
#pragma unroll
    for (int i = 0; i < 4; ++i) {
      const int rb = wave * 32 + i * 8;
      load_lds16(Kb + (size_t)(kb + rb + (lane >> 3)) * 64 +
                     (((lane & 7) ^ ((lane >> 3) & 7)) << 3),
                 &sK[rb * 64]);
    }
    // ---- DMA stage V^T: sV[d][slot s] = key-chunk s^(d&7)
#pragma unroll
    for (int i = 0; i < 4; ++i) {
      const int db = wave * 16 + i * 4;
      const int d = db + (lane >> 4);
      load_lds16(VTb + (size_t)d * 1024 + kb + (((lane & 15) ^ (d & 7)) << 3),
                 &sV[db * 128]);
    }
    __syncthreads();  // staged

    // ================= q-tile B (always active) =================
    {
      float sc[8][4];
#pragma unroll
      for (int n = 0; n < 8; ++n) {
        const int key = n * 16 + l16;
        bf16x8 kB0 = *(const bf16x8*)(&sK[key * 64 + ((quad ^ swq) << 3)]);
        bf16x8 kB1 = *(const bf16x8*)(&sK[key * 64 + (((quad + 4) ^ swq) << 3)]);
        f32x4 c = {};
        c = __builtin_amdgcn_mfma_f32_16x16x32_bf16(qA0B, kB0, c, 0, 0, 0);
        c = __builtin_amdgcn_mfma_f32_16x16x32_bf16(qA1B, kB1, c, 0, 0, 0);
#pragma unroll
        for (int r = 0; r < 4; ++r) sc[n][r] = c[r] * 0.125f;
      }
      if (kt == ktB_max) {
#pragma unroll
        for (int n = 0; n < 8; ++n) {
          const int kg = kb + n * 16 + l16;
#pragma unroll
          for (int r = 0; r < 4; ++r)
            if (kg > qbB + wave * 16 + quad * 4 + r) sc[n][r] = -1.0e30f;
        }
      }
#pragma unroll
      for (int n = 0; n < 8; ++n)
#pragma unroll
        for (int r = 0; r < 4; ++r) {
          float p = __expf(fminf(sc[n][r], 60.0f));
          sc[n][r] = p;
          psB[r] += p;
        }
      {
        const int kb8 = l16 >> 3, lo = l16 & 7;
#pragma unroll
        for (int n = 0; n < 8; ++n) {
          const int chunk = n * 2 + kb8;
#pragma unroll
          for (int r = 0; r < 4; ++r) {
            const int q = quad * 4 + r;
            pw[q * 128 + ((chunk ^ (q & 7)) << 3) + lo] = (__bf16)sc[n][r];
          }
        }
      }
#pragma unroll
      for (int cc = 0; cc < 4; ++cc) {
        bf16x8 pA = *(const bf16x8*)(&pw[l16 * 128 + (((cc * 4 + quad) ^ swq) << 3)]);
#pragma unroll
        for (int nt = 0; nt < 4; ++nt) {
          bf16x8 vB = *(const bf16x8*)(&sV[(nt * 16 + l16) * 128 +
                                           (((cc * 4 + quad) ^ swq) << 3)]);
          OB[nt] = __builtin_amdgcn_mfma_f32_16x16x32_bf16(pA, vB, OB[nt], 0, 0, 0);
        }
      }
    }

    // ================= q-tile A (active while kt <= ktA_max) =================
    if (kt <= ktA_max) {
      float sc[8][4];
#pragma unroll
      for (int n = 0; n < 8; ++n) {
        const int key = n * 16 + l16;
        bf16x8 kB0 = *(const bf16x8*)(&sK[key * 64 + ((quad ^ swq) << 3)]);
        bf16x8 kB1 = *(const bf16x8*)(&sK[key * 64 + (((quad + 4) ^ swq) << 3)]);
        f32x4 c = {};
        c = __builtin_amdgcn_mfma_f32_16x16x32_bf16(qA0A, kB0, c, 0, 0, 0);
        c = __builtin_amdgcn_mfma_f32_16x16x32_bf16(qA1A, kB1, c, 0, 0, 0);
#pragma unroll
        for (int r = 0; r < 4; ++r) sc[n][r] = c[r] * 0.125f;
      }
      if (kt == ktA_max) {
#pragma unroll
        for (int n = 0; n < 8; ++n) {
          const int kg = kb + n * 16 + l16;
#pragma unroll
          for (int r = 0; r < 4; ++r)
            if (kg > qbA + wave * 16 + quad * 4 + r) sc[n][r] = -1.0e30f;
        }
      }
#pragma unroll
      for (int n = 0; n < 8; ++n)
#pragma unroll
        for (int r = 0; r < 4; ++r) {
          float p = __expf(fminf(sc[n][r], 60.0f));
          sc[n][r] = p;
          psA[r] += p;
        }
      {
        const int kb8 = l16 >> 3, lo = l16 & 7;
#pragma unroll
        for (int n = 0; n < 8; ++n) {
          const int chunk = n * 2 + kb8;
#pragma unroll
          for (int r = 0; r < 4; ++r) {
            const int q = quad * 4 + r;
            pw[q * 128 + ((chunk ^ (q & 7)) << 3) + lo] = (__bf16)sc[n][r];
          }
        }
      }
#pragma unroll
      for (int cc = 0; cc < 4; ++cc) {
        bf16x8 pA = *(const bf16x8*)(&pw[l16 * 128 + (((cc * 4 + quad) ^ swq) << 3)]);
#pragma unroll
        for (int nt = 0; nt < 4; ++nt) {
          bf16x8 vB = *(const bf16x8*)(&sV[(nt * 16 + l16) * 128 +
                                           (((cc * 4 + quad) ^ swq) << 3)]);
          OA[nt] = __builtin_amdgcn_mfma_f32_16x16x32_bf16(pA, vB, OA[nt], 0, 0, 0);
        }
      }
    }
  }

  // ---- epilogue
  float invA[4], invB[4];
#pragma unroll
  for (int r = 0; r < 4; ++r) {
    float pa = psA[r], pb = psB[r];
    pa += __shfl_xor(pa, 1); pb += __shfl_xor(pb, 1);
    pa += __shfl_xor(pa, 2); pb += __shfl_xor(pb, 2);
    pa += __shfl_xor(pa, 4); pb += __shfl_xor(pb, 4);
    pa += __shfl_xor(pa, 8); pb += __shfl_xor(pb, 8);
    invA[r] = 1.0f / pa;
    invB[r] = 1.0f / pb;
  }
#pragma unroll
  for (int nt = 0; nt < 4; ++nt) {
#pragma unroll
    for (int r = 0; r < 4; ++r) {
      const int qA = qbA + wave * 16 + quad * 4 + r;
      const int qB = qbB + wave * 16 + quad * 4 + r;
      Aout[((size_t)b * 1024 + qA) * 1024 + h * 64 + nt * 16 + l16] =
          (__bf16)(OA[nt][r] * invA[r]);
      Aout[((size_t)b * 1024 + qB) * 1024 + h * 64 + nt * 16 + l16] =
          (__bf16)(OB[nt][r] * invB[r]);
    }
  }
}

// ---------------- launch ----------------
extern "C" void kernel_launch(void* const* d_in, const int* in_sizes, int n_in,
                              void* d_out, int out_size, void* d_ws,
                              size_t ws_size, hipStream_t stream) {
  const float* x      = (const float*)d_in[0];
  const float* w_attn = (const float*)d_in[1];
  const float* b_attn = (const float*)d_in[2];
  const float* w_proj = (const float*)d_in[3];
  const float* b_proj = (const float*)d_in[4];
  float* out = (float*)d_out;

  char* ws = (char*)d_ws;
  __bf16* WT_attn = (__bf16*)(ws);                  //  6 MB
  __bf16* WT_proj = (__bf16*)(ws + 6291456);        //  2 MB
  __bf16* Xb      = (__bf16*)(ws + 8388608);        //  8 MB (reused as VT)
  __bf16* Qp      = (__bf16*)(ws + 16777216);       //  8 MB [bh][s][64]
  __bf16* Kp      = (__bf16*)(ws + 25165824);       //  8 MB [bh][s][64]
  __bf16* Vr      = (__bf16*)(ws + 33554432);       //  8 MB [s_glob][1024]
  __bf16* Aattn   = (__bf16*)(ws + 41943040);       //  8 MB (end 50 MB)
  __bf16* VT      = Xb;  // x-as-bf16 dead after GEMM1

  prep<<<5120, 256, 0, stream>>>(x, w_attn, w_proj, Xb, WT_attn, WT_proj);
  gemm_qkv<<<dim3(24, 32), 256, 0, stream>>>(Xb, WT_attn, b_attn, Qp, Kp, Vr);
  transpose_v<<<1024, 256, 0, stream>>>(Vr, VT);
  attn_mfma<<<512, 256, 0, stream>>>(Qp, Kp, VT, Aattn);
  gemm_out<<<dim3(8, 32), 256, 0, stream>>>(Aattn, WT_proj, b_proj, out);
}